// Round 10
// baseline (530.566 us; speedup 1.0000x reference)
//
#include <hip/hip_runtime.h>
#include <hip/hip_bf16.h>
#include <hip/hip_fp16.h>

// GCN 3-layer pipeline on MI355X.
// out = A·(relu(BN(A·(relu(BN(A·(X@W1)))@W2)))@W3) + b3
// R10: (1) fill uses nontemporal stores (RFO-avoidance test on the scatter);
//      (2) memsets folded into wtrans_k (2 fewer serial dispatches);
//      (3) gemm2 reads B-frags from global Wt2 (no W-LDS, 17KB LDS like fused1).
//      Touch-law passes otherwise at measured HW random-access floor.

#define NPART 128
#define CAP 48

typedef _Float16 half8 __attribute__((ext_vector_type(8)));
typedef float f32x4 __attribute__((ext_vector_type(4)));

// ---------------- wtrans + workspace zeroing (one kernel) ----------------
// seg0: W1/W2 transpose (32768), seg1: W3 transpose+pad (8192),
// seg2: stats zero (4*NPART*128 = 65536), seg3: cnt zero (N).

__global__ void wtrans_k(const float* __restrict__ W1, __half* __restrict__ Wt1,
                         const float* __restrict__ W2, __half* __restrict__ Wt2,
                         const float* __restrict__ W3, __half* __restrict__ Wt3,
                         float* __restrict__ stats, int* __restrict__ cnt, int N) {
    int idx = blockIdx.x * 256 + threadIdx.x;
    if (idx < 32768) {
        const float* W = (idx < 16384) ? W1 : W2;
        __half* Wt = (idx < 16384) ? Wt1 : Wt2;
        int i = idx & 16383;
        int n = i >> 7, k = i & 127;
        Wt[n * 128 + k] = __float2half(W[k * 128 + n]);
    } else if (idx < 40960) {
        int i = idx - 32768;            // 64 x 128
        int n = i >> 7, k = i & 127;
        Wt3[n * 128 + k] = (n < 40) ? __float2half(W3[k * 40 + n]) : __half(0.0f);
    } else if (idx < 40960 + 4 * NPART * 128) {
        stats[idx - 40960] = 0.f;
    } else if (idx < 40960 + 4 * NPART * 128 + N) {
        cnt[idx - 40960 - 4 * NPART * 128] = 0;
    }
}

// ---------------- fused: gemm1 (MFMA, fp32 in, no BN) + padded-CSR fill ----------------

__global__ __launch_bounds__(256) void fused1_k(
    const float* __restrict__ A, const __half* __restrict__ Wt, __half* __restrict__ Yh,
    int M, int gemmBlocks,
    const int* __restrict__ src, const int* __restrict__ dst,
    const float* __restrict__ ew, int* __restrict__ cnt, int* __restrict__ epair, int E) {
    __shared__ __half At[64][136];
    int tid = threadIdx.x;

    if (blockIdx.x < gemmBlocks) {
        int row0 = blockIdx.x * 64;
        #pragma unroll
        for (int t = 0; t < 8; ++t) {
            int i = tid + t * 256;
            int r = i >> 5, ch = i & 31;
            int grow = row0 + r;
            int gk = ch * 4;
            float4 a = make_float4(0.f, 0.f, 0.f, 0.f);
            if (grow < M) a = *(const float4*)&A[(size_t)grow * 128 + gk];
            *(__half2*)&At[r][gk + 0] = __floats2half2_rn(a.x, a.y);
            *(__half2*)&At[r][gk + 2] = __floats2half2_rn(a.z, a.w);
        }
        __syncthreads();

        int wv = tid >> 6;
        int rw = wv & 1;
        int cw = wv >> 1;
        int lane = tid & 63;
        int ml = lane & 15;
        int quad = lane >> 4;

        f32x4 acc[2][4];
        #pragma unroll
        for (int i = 0; i < 2; ++i)
            #pragma unroll
            for (int j = 0; j < 4; ++j)
                acc[i][j] = (f32x4){0.f, 0.f, 0.f, 0.f};

        #pragma unroll
        for (int kc = 0; kc < 4; ++kc) {
            int k0 = kc * 32 + quad * 8;
            half8 a0 = *(const half8*)&At[rw * 32 + ml][k0];
            half8 a1 = *(const half8*)&At[rw * 32 + 16 + ml][k0];
            #pragma unroll
            for (int tc = 0; tc < 4; ++tc) {
                half8 b = *(const half8*)&Wt[(size_t)(cw * 64 + tc * 16 + ml) * 128 + k0];
                acc[0][tc] = __builtin_amdgcn_mfma_f32_16x16x32_f16(a0, b, acc[0][tc], 0, 0, 0);
                acc[1][tc] = __builtin_amdgcn_mfma_f32_16x16x32_f16(a1, b, acc[1][tc], 0, 0, 0);
            }
        }

        #pragma unroll
        for (int tr = 0; tr < 2; ++tr)
            #pragma unroll
            for (int tc = 0; tc < 4; ++tc)
                #pragma unroll
                for (int r = 0; r < 4; ++r) {
                    int grow = row0 + rw * 32 + tr * 16 + quad * 4 + r;
                    int col = cw * 64 + tc * 16 + ml;
                    if (grow < M) Yh[(size_t)grow * 128 + col] = __float2half(acc[tr][tc][r]);
                }
    } else {
        int e = (blockIdx.x - gemmBlocks) * 256 + tid;
        if (e < E) {
            int v = dst[e];
            int j = atomicAdd(&cnt[v], 1);
            // pack (src, weight-bits) into 64b and nontemporal-store (no RFO)
            unsigned long long pk = (unsigned long long)(unsigned)src[e] |
                                    ((unsigned long long)(unsigned)__float_as_int(ew[e]) << 32);
            __builtin_nontemporal_store(pk, (unsigned long long*)&epair[2 * ((size_t)v * CAP + j)]);
        }
    }
}

// ---------------- MFMA-fp16 GEMM, fp16 A input + fused BN/ReLU (layer 2) ----------------
// B-frags read straight from global Wt (32KB, L1-resident). LDS = At only.

__global__ __launch_bounds__(256) void gemm128_f16in_k(
    const __half* __restrict__ A, const __half* __restrict__ Wt, __half* __restrict__ Yh,
    int M, const float* __restrict__ scale, const float* __restrict__ shift) {
    __shared__ __half At[64][136];
    int tid = threadIdx.x;
    int row0 = blockIdx.x * 64;

    #pragma unroll
    for (int t = 0; t < 4; ++t) {
        int i = tid + t * 256;
        int r = i >> 4, ch = i & 15;
        int grow = row0 + r;
        int gk = ch * 8;
        float4 raw = make_float4(0.f, 0.f, 0.f, 0.f);
        if (grow < M) raw = *(const float4*)&A[(size_t)grow * 128 + gk];
        __half2* hp = (__half2*)&raw;
        #pragma unroll
        for (int j = 0; j < 4; ++j) {
            float2 x = __half22float2(hp[j]);
            int c = gk + 2 * j;
            x.x = fmaxf(x.x * scale[c + 0] + shift[c + 0], 0.f);
            x.y = fmaxf(x.y * scale[c + 1] + shift[c + 1], 0.f);
            *(__half2*)&At[r][c] = __floats2half2_rn(x.x, x.y);
        }
    }
    __syncthreads();

    int wv = tid >> 6;
    int rw = wv & 1;
    int cw = wv >> 1;
    int lane = tid & 63;
    int ml = lane & 15;
    int quad = lane >> 4;

    f32x4 acc[2][4];
    #pragma unroll
    for (int i = 0; i < 2; ++i)
        #pragma unroll
        for (int j = 0; j < 4; ++j)
            acc[i][j] = (f32x4){0.f, 0.f, 0.f, 0.f};

    #pragma unroll
    for (int kc = 0; kc < 4; ++kc) {
        int k0 = kc * 32 + quad * 8;
        half8 a0 = *(const half8*)&At[rw * 32 + ml][k0];
        half8 a1 = *(const half8*)&At[rw * 32 + 16 + ml][k0];
        #pragma unroll
        for (int tc = 0; tc < 4; ++tc) {
            half8 b = *(const half8*)&Wt[(size_t)(cw * 64 + tc * 16 + ml) * 128 + k0];
            acc[0][tc] = __builtin_amdgcn_mfma_f32_16x16x32_f16(a0, b, acc[0][tc], 0, 0, 0);
            acc[1][tc] = __builtin_amdgcn_mfma_f32_16x16x32_f16(a1, b, acc[1][tc], 0, 0, 0);
        }
    }

    #pragma unroll
    for (int tr = 0; tr < 2; ++tr)
        #pragma unroll
        for (int tc = 0; tc < 4; ++tc)
            #pragma unroll
            for (int r = 0; r < 4; ++r) {
                int grow = row0 + rw * 32 + tr * 16 + quad * 4 + r;
                int col = cw * 64 + tc * 16 + ml;
                if (grow < M) Yh[(size_t)grow * 128 + col] = __float2half(acc[tr][tc][r]);
            }
}

// ---------------- MFMA GEMM layer-3: fp16 A (BN/ReLU fused) x Wt3(64x128) -> fp32 40ch ----------------

__global__ __launch_bounds__(256) void gemm40_mfma_k(
    const __half* __restrict__ A, const __half* __restrict__ Wt3, float* __restrict__ Y,
    int M, const float* __restrict__ scale, const float* __restrict__ shift) {
    __shared__ __half At[64][136];
    int tid = threadIdx.x;
    int row0 = blockIdx.x * 64;

    #pragma unroll
    for (int t = 0; t < 4; ++t) {
        int i = tid + t * 256;
        int r = i >> 4, ch = i & 15;
        int grow = row0 + r;
        int gk = ch * 8;
        float4 raw = make_float4(0.f, 0.f, 0.f, 0.f);
        if (grow < M) raw = *(const float4*)&A[(size_t)grow * 128 + gk];
        __half2* hp = (__half2*)&raw;
        #pragma unroll
        for (int j = 0; j < 4; ++j) {
            float2 x = __half22float2(hp[j]);
            int c = gk + 2 * j;
            x.x = fmaxf(x.x * scale[c + 0] + shift[c + 0], 0.f);
            x.y = fmaxf(x.y * scale[c + 1] + shift[c + 1], 0.f);
            *(__half2*)&At[r][c] = __floats2half2_rn(x.x, x.y);
        }
    }
    __syncthreads();

    int wv = tid >> 6;
    int rw = wv & 1;
    int cw = wv >> 1;
    int lane = tid & 63;
    int ml = lane & 15;
    int quad = lane >> 4;

    f32x4 acc[2][2];
    #pragma unroll
    for (int i = 0; i < 2; ++i)
        #pragma unroll
        for (int j = 0; j < 2; ++j)
            acc[i][j] = (f32x4){0.f, 0.f, 0.f, 0.f};

    #pragma unroll
    for (int kc = 0; kc < 4; ++kc) {
        int k0 = kc * 32 + quad * 8;
        half8 a0 = *(const half8*)&At[rw * 32 + ml][k0];
        half8 a1 = *(const half8*)&At[rw * 32 + 16 + ml][k0];
        #pragma unroll
        for (int tc = 0; tc < 2; ++tc) {
            half8 b = *(const half8*)&Wt3[(size_t)(cw * 32 + tc * 16 + ml) * 128 + k0];
            acc[0][tc] = __builtin_amdgcn_mfma_f32_16x16x32_f16(a0, b, acc[0][tc], 0, 0, 0);
            acc[1][tc] = __builtin_amdgcn_mfma_f32_16x16x32_f16(a1, b, acc[1][tc], 0, 0, 0);
        }
    }

    #pragma unroll
    for (int tr = 0; tr < 2; ++tr)
        #pragma unroll
        for (int tc = 0; tc < 2; ++tc) {
            int col = cw * 32 + tc * 16 + ml;
            if (col < 40) {
                #pragma unroll
                for (int r = 0; r < 4; ++r) {
                    int grow = row0 + rw * 32 + tr * 16 + quad * 4 + r;
                    if (grow < M) Y[(size_t)grow * 40 + col] = acc[tr][tc][r];
                }
            }
        }
}

// ---------------- SpMM 128ch: pure gather over padded CSR, fp16 in/out ----------------

__global__ __launch_bounds__(256) void spmm128_k(
    const int* __restrict__ cnt, const int* __restrict__ epair,
    const __half* __restrict__ X, __half* __restrict__ H, int n) {
    int lane = threadIdx.x & 63;
    int v = blockIdx.x * 4 + (threadIdx.x >> 6);
    if (v >= n) return;
    const __half2* X2 = (const __half2*)X;
    int deg = cnt[v];
    const int4* ep4 = (const int4*)&epair[2 * (size_t)v * CAP];
    float2 acc = {0.f, 0.f};
    int i = 0;
    int4 q0, q1, q2, q3;
    bool have = (i + 8 <= deg);
    if (have) { q0 = ep4[0]; q1 = ep4[1]; q2 = ep4[2]; q3 = ep4[3]; }
    while (have) {
        int u0 = q0.x, u1 = q0.z, u2 = q1.x, u3 = q1.z;
        int u4 = q2.x, u5 = q2.z, u6 = q3.x, u7 = q3.z;
        float w0 = __int_as_float(q0.y), w1 = __int_as_float(q0.w);
        float w2 = __int_as_float(q1.y), w3 = __int_as_float(q1.w);
        float w4 = __int_as_float(q2.y), w5 = __int_as_float(q2.w);
        float w6 = __int_as_float(q3.y), w7 = __int_as_float(q3.w);
        __half2 h0 = X2[(size_t)u0 * 64 + lane];
        __half2 h1 = X2[(size_t)u1 * 64 + lane];
        __half2 h2 = X2[(size_t)u2 * 64 + lane];
        __half2 h3 = X2[(size_t)u3 * 64 + lane];
        __half2 h4 = X2[(size_t)u4 * 64 + lane];
        __half2 h5 = X2[(size_t)u5 * 64 + lane];
        __half2 h6 = X2[(size_t)u6 * 64 + lane];
        __half2 h7 = X2[(size_t)u7 * 64 + lane];
        i += 8;
        have = (i + 8 <= deg);
        if (have) { q0 = ep4[i / 2]; q1 = ep4[i / 2 + 1]; q2 = ep4[i / 2 + 2]; q3 = ep4[i / 2 + 3]; }
        float2 x0 = __half22float2(h0);
        float2 x1 = __half22float2(h1);
        float2 x2 = __half22float2(h2);
        float2 x3 = __half22float2(h3);
        float2 x4 = __half22float2(h4);
        float2 x5 = __half22float2(h5);
        float2 x6 = __half22float2(h6);
        float2 x7 = __half22float2(h7);
        acc.x += w0 * x0.x; acc.y += w0 * x0.y;
        acc.x += w1 * x1.x; acc.y += w1 * x1.y;
        acc.x += w2 * x2.x; acc.y += w2 * x2.y;
        acc.x += w3 * x3.x; acc.y += w3 * x3.y;
        acc.x += w4 * x4.x; acc.y += w4 * x4.y;
        acc.x += w5 * x5.x; acc.y += w5 * x5.y;
        acc.x += w6 * x6.x; acc.y += w6 * x6.y;
        acc.x += w7 * x7.x; acc.y += w7 * x7.y;
    }
    for (; i + 2 <= deg; i += 2) {
        int4 q = ep4[i / 2];
        float2 xa = __half22float2(X2[(size_t)q.x * 64 + lane]);
        float2 xb = __half22float2(X2[(size_t)q.z * 64 + lane]);
        float wa = __int_as_float(q.y), wb = __int_as_float(q.w);
        acc.x += wa * xa.x; acc.y += wa * xa.y;
        acc.x += wb * xb.x; acc.y += wb * xb.y;
    }
    if (i < deg) {
        int2 p = ((const int2*)ep4)[i];
        float2 x = __half22float2(X2[(size_t)p.x * 64 + lane]);
        float wv = __int_as_float(p.y);
        acc.x += wv * x.x; acc.y += wv * x.y;
    }
    ((__half2*)H)[(size_t)v * 64 + lane] = __floats2half2_rn(acc.x, acc.y);
}

// ---------------- streaming BN-stat partials over fp16 H ----------------

__global__ __launch_bounds__(256) void stats_k(
    const __half* __restrict__ H, int n,
    float* __restrict__ psum, float* __restrict__ psq) {
    __shared__ float ls[128];
    __shared__ float lq[128];
    int tid = threadIdx.x;
    if (tid < 128) { ls[tid] = 0.f; lq[tid] = 0.f; }
    __syncthreads();
    int lane = tid & 63;
    int w = tid >> 6;
    const __half2* H2 = (const __half2*)H;
    float s0 = 0.f, s1 = 0.f, q0 = 0.f, q1 = 0.f;
    for (int r = blockIdx.x * 4 + w; r < n; r += gridDim.x * 4) {
        float2 x = __half22float2(H2[(size_t)r * 64 + lane]);
        s0 += x.x; s1 += x.y;
        q0 += x.x * x.x; q1 += x.y * x.y;
    }
    atomicAdd(&ls[2 * lane + 0], s0);
    atomicAdd(&ls[2 * lane + 1], s1);
    atomicAdd(&lq[2 * lane + 0], q0);
    atomicAdd(&lq[2 * lane + 1], q1);
    __syncthreads();
    if (tid < 128) {
        int p = blockIdx.x & (NPART - 1);
        atomicAdd(&psum[p * 128 + tid], ls[tid]);
        atomicAdd(&psq[p * 128 + tid], lq[tid]);
    }
}

// ---------------- SpMM layer-3 (fp32, 40 ch) over padded CSR ----------------

__global__ __launch_bounds__(256) void spmm40_k(
    const int* __restrict__ cnt, const int* __restrict__ epair,
    const float* __restrict__ X, float* __restrict__ H, int n,
    const float* __restrict__ bias) {
    int lane = threadIdx.x & 63;
    int v = blockIdx.x * 4 + (threadIdx.x >> 6);
    if (v >= n) return;
    int deg = cnt[v];
    const int2* ep = (const int2*)&epair[2 * (size_t)v * CAP];
    bool al = lane < 40;
    float acc = 0.f;
    int i = 0;
    for (; i + 4 <= deg; i += 4) {
        int2 p0 = ep[i];
        int2 p1 = ep[i + 1];
        int2 p2 = ep[i + 2];
        int2 p3 = ep[i + 3];
        if (al) {
            float x0 = X[(size_t)p0.x * 40 + lane];
            float x1 = X[(size_t)p1.x * 40 + lane];
            float x2 = X[(size_t)p2.x * 40 + lane];
            float x3 = X[(size_t)p3.x * 40 + lane];
            acc += __int_as_float(p0.y) * x0;
            acc += __int_as_float(p1.y) * x1;
            acc += __int_as_float(p2.y) * x2;
            acc += __int_as_float(p3.y) * x3;
        }
    }
    for (; i < deg; ++i) {
        int2 p = ep[i];
        if (al) acc += __int_as_float(p.y) * X[(size_t)p.x * 40 + lane];
    }
    if (al) H[(size_t)v * 40 + lane] = acc + bias[lane];
}

// ---------------- BN stats -> scale/shift ----------------

__global__ void bnstats_k(const float* __restrict__ ps, const float* __restrict__ pq,
                          const float* __restrict__ gamma, const float* __restrict__ beta,
                          float* __restrict__ scale, float* __restrict__ shift, int n) {
    int c = threadIdx.x;
    float s = 0.f, q = 0.f;
    for (int p = 0; p < NPART; ++p) {
        s += ps[p * 128 + c];
        q += pq[p * 128 + c];
    }
    float mean = s / (float)n;
    float var = q / (float)n - mean * mean;
    float sc = gamma[c] / sqrtf(var + 1e-5f);
    scale[c] = sc;
    shift[c] = beta[c] - mean * sc;
}

// ---------------- launch ----------------

extern "C" void kernel_launch(void* const* d_in, const int* in_sizes, int n_in,
                              void* d_out, int out_size, void* d_ws, size_t ws_size,
                              hipStream_t stream) {
    const float* feat = (const float*)d_in[0];
    const int* esrc   = (const int*)d_in[1];
    const int* edst   = (const int*)d_in[2];
    const float* ew   = (const float*)d_in[3];
    const float* W1   = (const float*)d_in[4];
    const float* W2   = (const float*)d_in[5];
    const float* W3   = (const float*)d_in[6];
    const float* b3   = (const float*)d_in[7];
    const float* g1   = (const float*)d_in[8];
    const float* be1  = (const float*)d_in[9];
    const float* g2   = (const float*)d_in[10];
    const float* be2  = (const float*)d_in[11];
    float* out = (float*)d_out;

    const int N = in_sizes[0] / 128;
    const int E = in_sizes[1];

    char* w = (char*)d_ws;
    size_t o = 0;
    auto alloc = [&](size_t b) { size_t r = o; o = (o + b + 255) & ~(size_t)255; return r; };
    int* cnt      = (int*)(w + alloc((size_t)N * 4));
    int* epair    = (int*)(w + alloc((size_t)N * CAP * 8));
    float* stats  = (float*)(w + alloc((size_t)4 * NPART * 128 * 4));
    float* sc1    = (float*)(w + alloc(128 * 4));
    float* sh1    = (float*)(w + alloc(128 * 4));
    float* sc2    = (float*)(w + alloc(128 * 4));
    float* sh2    = (float*)(w + alloc(128 * 4));
    __half* Wt1   = (__half*)(w + alloc(128 * 128 * 2));
    __half* Wt2   = (__half*)(w + alloc(128 * 128 * 2));
    __half* Wt3   = (__half*)(w + alloc(64 * 128 * 2));
    __half* Yh    = (__half*)(w + alloc((size_t)N * 128 * 2));
    __half* Hh    = (__half*)(w + alloc((size_t)N * 128 * 2));
    float* Y40    = (float*)Yh;   // alias: Y2 dead once gemm40 runs (reads Hh)
    float* p1s = stats;
    float* p1q = stats + NPART * 128;
    float* p2s = stats + 2 * NPART * 128;
    float* p2q = stats + 3 * NPART * 128;

    int zthreads = 40960 + 4 * NPART * 128 + N;
    wtrans_k<<<(zthreads + 255) / 256, 256, 0, stream>>>(W1, Wt1, W2, Wt2, W3, Wt3,
                                                         stats, cnt, N);

    int gb64 = (N + 63) / 64;
    int fillb = (E + 255) / 256;
    int sb = (N + 3) / 4;

    // layer 1 GEMM overlapped with CSR fill
    fused1_k<<<gb64 + fillb, 256, 0, stream>>>(feat, Wt1, Yh, N, gb64,
                                               esrc, edst, ew, cnt, epair, E);
    spmm128_k<<<sb, 256, 0, stream>>>(cnt, epair, Yh, Hh, N);
    stats_k<<<512, 256, 0, stream>>>(Hh, N, p1s, p1q);
    bnstats_k<<<1, 128, 0, stream>>>(p1s, p1q, g1, be1, sc1, sh1, N);

    gemm128_f16in_k<<<gb64, 256, 0, stream>>>(Hh, Wt2, Yh, N, sc1, sh1);
    spmm128_k<<<sb, 256, 0, stream>>>(cnt, epair, Yh, Hh, N);
    stats_k<<<512, 256, 0, stream>>>(Hh, N, p2s, p2q);
    bnstats_k<<<1, 128, 0, stream>>>(p2s, p2q, g2, be2, sc2, sh2, N);

    gemm40_mfma_k<<<gb64, 256, 0, stream>>>(Hh, Wt3, Y40, N, sc2, sh2);
    spmm40_k<<<sb, 256, 0, stream>>>(cnt, epair, Y40, out, N, b3);
}